// Round 1
// baseline (1366.793 us; speedup 1.0000x reference)
//
#include <hip/hip_runtime.h>
#include <stdint.h>

#define L_SEQ 243
#define HID   256
#define CHK   81
#define NJ    17
#define NB    1088   // 64*17 sequences

typedef short bf16x8 __attribute__((ext_vector_type(8)));
typedef float f32x4  __attribute__((ext_vector_type(4)));

__device__ __forceinline__ unsigned short f2bf(float f) {
  unsigned int u = __float_as_uint(f);
  u = (u + 0x7fffu + ((u >> 16) & 1u)) >> 16;
  return (unsigned short)u;
}

// ---------------- ws layout (bytes) ----------------
// Qw  bf16 [1088][243][256]           @ 0          (135,364,608)
// Kw  bf16 [1088][243][256]           @ 135364608
// Vt  bf16 [1088][256][248]  (pos-padded to 248)  @ 270729216  (138,149,888)
// Wt  bf16 [768][256]                 @ 408879104  (393,216)
// tables fp32 cu/su/cd/sd [243][128]  @ 409272320  (4*124,416)
// gpow fp32 [17][256]                 @ 409769984  (17,408)
#define OFF_Q   0ull
#define OFF_K   135364608ull
#define OFF_V   270729216ull
#define OFF_WT  408879104ull
#define OFF_TAB 409272320ull
#define OFF_GP  409769984ull
#define WS_NEED 409787392ull

// ---------------- kernel 1: precompute ----------------
__global__ void prep_kernel(const float* __restrict__ Wq, const float* __restrict__ Wk,
                            const float* __restrict__ Wv, const float* __restrict__ gamma,
                            unsigned short* __restrict__ Wt,
                            float* __restrict__ cu, float* __restrict__ su,
                            float* __restrict__ cd, float* __restrict__ sd,
                            float* __restrict__ gp) {
  int id = blockIdx.x * 256 + threadIdx.x;
  if (id < 768 * 256) {
    int n = id >> 8, k = id & 255;
    const float* W = (n < 256) ? Wq : (n < 512 ? Wk : Wv);
    Wt[n * 256 + k] = f2bf(W[k * 256 + (n & 255)]);
  } else if (id < 768 * 256 + L_SEQ * 128) {
    int r = id - 768 * 256;
    int p = r >> 7, h = r & 127;
    float base  = (2.0f * h + 102.4f) / 358.4f;          // (2h + 0.4*256)/(1.4*256)
    float scale = powf(base, (float)p * (1.0f / 512.0f));
    float invf  = powf(10000.0f, -(float)h * (1.0f / 128.0f));
    float ang   = (float)p * invf;
    float s, c; sincosf(ang, &s, &c);
    cu[p * 128 + h] = c * scale;  su[p * 128 + h] = s * scale;
    cd[p * 128 + h] = c / scale;  sd[p * 128 + h] = s / scale;
  } else if (id < 768 * 256 + L_SEQ * 128 + NJ * 256) {
    int r = id - (768 * 256 + L_SEQ * 128);
    int j = r >> 8, d = r & 255;
    gp[r] = (d < L_SEQ) ? powf(gamma[j], (float)d) : 0.0f;
  }
}

// ---------------- kernel 2: QKV projection + xpos ----------------
__global__ __launch_bounds__(256, 2)
void proj_kernel(const float* __restrict__ X, const unsigned short* __restrict__ Wt,
                 const float* __restrict__ cu, const float* __restrict__ su,
                 const float* __restrict__ cd, const float* __restrict__ sd,
                 unsigned short* __restrict__ Qw, unsigned short* __restrict__ Kw,
                 unsigned short* __restrict__ Vt) {
  __shared__ __align__(16) unsigned short Xs[128 * 264];  // 128 rows x 256 k (+8 pad)
  __shared__ __align__(16) unsigned short Ws[128 * 40];   // 128 n x 32 k (+8 pad)
  int tid = threadIdx.x;
  int gid = blockIdx.x;
  int b = gid % NB, mt = gid / NB;
  int m0 = mt * 128;
  int wid = tid >> 6, lane = tid & 63, ln = lane & 15, quad = lane >> 4;
  int mw = (wid >> 1) * 64, nw = (wid & 1) * 64;
  const float* Xb = X + (size_t)b * (L_SEQ * HID);

  // stage X tile -> bf16 LDS (zero-pad rows >= 243)
  for (int it = 0; it < 32; ++it) {
    int idx = it * 256 + tid;
    int r = idx >> 6, c4 = (idx & 63) << 2;
    int p = m0 + r;
    float4 v = make_float4(0.f, 0.f, 0.f, 0.f);
    if (p < L_SEQ) v = *(const float4*)(Xb + p * HID + c4);
    ushort4 h;
    h.x = f2bf(v.x); h.y = f2bf(v.y); h.z = f2bf(v.z); h.w = f2bf(v.w);
    *(ushort4*)&Xs[r * 264 + c4] = h;
  }

  for (int nt = 0; nt < 6; ++nt) {
    int n0 = nt * 128;
    f32x4 acc[4][4] = {};
    for (int ks = 0; ks < 8; ++ks) {
      __syncthreads();           // protects Xs (first) and Ws reuse
      for (int it = 0; it < 2; ++it) {
        int idx = it * 256 + tid;
        int r = idx >> 2, seg = idx & 3;
        uint4 w = *(const uint4*)(Wt + (n0 + r) * 256 + ks * 32 + seg * 8);
        *(uint4*)&Ws[r * 40 + seg * 8] = w;
      }
      __syncthreads();
      bf16x8 a[4], bb[4];
      for (int t = 0; t < 4; ++t)
        a[t] = *(const bf16x8*)&Xs[(mw + 16 * t + ln) * 264 + ks * 32 + quad * 8];
      for (int t = 0; t < 4; ++t)
        bb[t] = *(const bf16x8*)&Ws[(nw + 16 * t + ln) * 40 + quad * 8];
      for (int i = 0; i < 4; ++i)
        for (int j = 0; j < 4; ++j)
          acc[i][j] = __builtin_amdgcn_mfma_f32_16x16x32_bf16(a[i], bb[j], acc[i][j], 0, 0, 0);
    }
    // epilogue: C/D layout col=lane&15, row=quad*4+reg (m89/m91-verified)
    if (nt < 4) {  // Q (nt 0,1) or K (nt 2,3): xpos then row-major bf16 store
      bool isQ = (nt < 2);
      const float* ct = isQ ? cu : cd;
      const float* st = isQ ? su : sd;
      unsigned short* Dst = isQ ? Qw : Kw;
      for (int i = 0; i < 4; ++i) {
        int pb = m0 + mw + 16 * i + quad * 4;
        for (int j = 0; j < 4; ++j) {
          int n = n0 + nw + 16 * j + ln;
          int d = n & 255, h = d >> 1;
          for (int r = 0; r < 4; ++r) {
            float v  = acc[i][j][r];
            float pv = __shfl_xor(v, 1, 64);  // partner column (lane^1 holds col^1)
            int pp = pb + r;
            int tp = (pp < L_SEQ) ? pp : 0;
            float c = ct[tp * 128 + h], s = st[tp * 128 + h];
            float o = (d & 1) ? (v * c + pv * s) : (v * c - pv * s);
            if (pp < L_SEQ) Dst[((size_t)b * L_SEQ + pp) * 256 + d] = f2bf(o);
          }
        }
      }
    } else {  // V: store transposed Vt[b][d][pos], pos-padded stride 248
      for (int i = 0; i < 4; ++i) {
        int p0 = m0 + mw + 16 * i + quad * 4;
        for (int j = 0; j < 4; ++j) {
          int d = (n0 - 512) + nw + 16 * j + ln;
          ushort4 pk;
          pk.x = f2bf(acc[i][j][0]); pk.y = f2bf(acc[i][j][1]);
          pk.z = f2bf(acc[i][j][2]); pk.w = f2bf(acc[i][j][3]);
          size_t base = ((size_t)b * 256 + d) * 248 + p0;
          if (p0 + 3 < L_SEQ) {
            *(ushort4*)(Vt + base) = pk;          // 8B aligned: 248*2%8==0, p0%4==0
          } else {
            unsigned short tmp[4] = {pk.x, pk.y, pk.z, pk.w};
            for (int r = 0; r < 4; ++r) if (p0 + r < L_SEQ) Vt[base + r] = tmp[r];
          }
        }
      }
    }
  }
}

// ---------------- kernel 3: decay-masked attention (linear, no softmax) ----------------
__global__ __launch_bounds__(256, 2)
void attn_kernel(const unsigned short* __restrict__ Qw, const unsigned short* __restrict__ Kw,
                 const unsigned short* __restrict__ Vt, const float* __restrict__ gpow,
                 float* __restrict__ Out) {
  __shared__ __align__(16) unsigned short Qs[64 * 264];
  __shared__ __align__(16) unsigned short Ks[32 * 264];
  __shared__ __align__(16) unsigned short Vts[256 * 40]; // [d][key] (+8 pad)
  __shared__ __align__(16) unsigned short Ps[64 * 40];   // P in bf16, C->A layout round trip
  __shared__ float gp[256];
  int tid = threadIdx.x;
  int gid = blockIdx.x;
  int b = gid % NB, qb = gid / NB;   // qblock-major: a seq's 4 blocks share an XCD (1088%8==0)
  int wid = tid >> 6, lane = tid & 63, ln = lane & 15, quad = lane >> 4;

  gp[tid] = gpow[(b % NJ) * 256 + tid];

  // stage Q block (64 x 256), zero-pad rows >= 243
  for (int it = 0; it < 8; ++it) {
    int idx = it * 256 + tid;
    int r = idx >> 5, seg = idx & 31;
    int p = qb * 64 + r;
    uint4 v = make_uint4(0, 0, 0, 0);
    if (p < L_SEQ) v = *(const uint4*)(Qw + ((size_t)b * L_SEQ + p) * 256 + seg * 8);
    *(uint4*)&Qs[r * 264 + seg * 8] = v;
  }

  f32x4 o[16] = {};
  for (int kb = 0; kb < 8; ++kb) {
    int m0 = kb * 32;
    __syncthreads();  // previous PV reads done before restage
    for (int it = 0; it < 4; ++it) {  // K block 32 x 256
      int idx = it * 256 + tid;
      int r = idx >> 5, seg = idx & 31;
      int p = m0 + r;
      uint4 v = make_uint4(0, 0, 0, 0);
      if (p < L_SEQ) v = *(const uint4*)(Kw + ((size_t)b * L_SEQ + p) * 256 + seg * 8);
      *(uint4*)&Ks[r * 264 + seg * 8] = v;
    }
    for (int it = 0; it < 4; ++it) {  // Vt block 256 x 32
      int idx = it * 256 + tid;
      int r = idx >> 2, seg = idx & 3;
      int p0 = m0 + seg * 8;
      const unsigned short* src = Vt + ((size_t)b * 256 + r) * 248 + p0;
      uint4 v;
      if (p0 + 8 <= L_SEQ) {
        v = *(const uint4*)src;
      } else {
        union { unsigned short u[8]; uint4 v4; } tt;
        for (int e = 0; e < 8; ++e) tt.u[e] = (p0 + e < L_SEQ) ? src[e] : 0;
        v = tt.v4;
      }
      *(uint4*)&Vts[r * 40 + seg * 8] = v;
    }
    __syncthreads();
    // S = Q K^T : 16 query rows per wave x 32 keys
    f32x4 s[2] = {};
    for (int ks = 0; ks < 8; ++ks) {
      bf16x8 aq = *(const bf16x8*)&Qs[(wid * 16 + ln) * 264 + ks * 32 + quad * 8];
      for (int t = 0; t < 2; ++t) {
        bf16x8 bk = *(const bf16x8*)&Ks[(t * 16 + ln) * 264 + ks * 32 + quad * 8];
        s[t] = __builtin_amdgcn_mfma_f32_16x16x32_bf16(aq, bk, s[t], 0, 0, 0);
      }
    }
    // decay in fp32, P -> bf16 -> LDS
    for (int t = 0; t < 2; ++t) {
      int m = m0 + t * 16 + ln;
      for (int r = 0; r < 4; ++r) {
        int iloc = wid * 16 + quad * 4 + r;
        int i = qb * 64 + iloc;
        int lim = (i / CHK + 1) * CHK; if (lim > L_SEQ) lim = L_SEQ;
        int ad = (i > m) ? (i - m) : (m - i);
        float f = (m < lim) ? gp[ad] : 0.0f;
        Ps[iloc * 40 + t * 16 + ln] = f2bf(s[t][r] * f);
      }
    }
    __syncthreads();
    // O += P V  (K=32 keys in one MFMA k-step; 16 d-subtiles)
    bf16x8 ap = *(const bf16x8*)&Ps[(wid * 16 + ln) * 40 + quad * 8];
    for (int nt = 0; nt < 16; ++nt) {
      bf16x8 bv = *(const bf16x8*)&Vts[(nt * 16 + ln) * 40 + quad * 8];
      o[nt] = __builtin_amdgcn_mfma_f32_16x16x32_bf16(ap, bv, o[nt], 0, 0, 0);
    }
  }
  // epilogue: fp32 store
  for (int nt = 0; nt < 16; ++nt) {
    int d = nt * 16 + ln;
    for (int r = 0; r < 4; ++r) {
      int p = qb * 64 + wid * 16 + quad * 4 + r;
      if (p < L_SEQ) Out[((size_t)b * L_SEQ + p) * 256 + d] = o[nt][r];
    }
  }
}

extern "C" void kernel_launch(void* const* d_in, const int* in_sizes, int n_in,
                              void* d_out, int out_size, void* d_ws, size_t ws_size,
                              hipStream_t stream) {
  const float* X     = (const float*)d_in[0];
  const float* Wq    = (const float*)d_in[1];
  const float* Wk    = (const float*)d_in[2];
  const float* Wv    = (const float*)d_in[3];
  const float* gamma = (const float*)d_in[4];
  if (ws_size < WS_NEED) return;  // deterministic guard (same work every call)

  char* ws = (char*)d_ws;
  unsigned short* Qw  = (unsigned short*)(ws + OFF_Q);
  unsigned short* Kw  = (unsigned short*)(ws + OFF_K);
  unsigned short* Vtw = (unsigned short*)(ws + OFF_V);
  unsigned short* Wt  = (unsigned short*)(ws + OFF_WT);
  float* cu = (float*)(ws + OFF_TAB);
  float* su = cu + L_SEQ * 128;
  float* cd = su + L_SEQ * 128;
  float* sd = cd + L_SEQ * 128;
  float* gp = (float*)(ws + OFF_GP);

  hipLaunchKernelGGL(prep_kernel, dim3(907), dim3(256), 0, stream,
                     Wq, Wk, Wv, gamma, Wt, cu, su, cd, sd, gp);
  hipLaunchKernelGGL(proj_kernel, dim3(2176), dim3(256), 0, stream,
                     X, Wt, cu, su, cd, sd, Qw, Kw, Vtw);
  hipLaunchKernelGGL(attn_kernel, dim3(4352), dim3(256), 0, stream,
                     Qw, Kw, Vtw, gp, (float*)d_out);
}